// Round 1
// baseline (4798.033 us; speedup 1.0000x reference)
//
#include <hip/hip_runtime.h>
#include <stdint.h>

#define NROWS 16384
#define NZ    8192
#define NCLUST 16
#define DSUB  512

typedef __attribute__((ext_vector_type(8))) short short8;
typedef __attribute__((ext_vector_type(4))) float floatx4;

__device__ __forceinline__ unsigned short f2bf(float f) {
  unsigned int u = __float_as_uint(f);
  u += 0x7fffu + ((u >> 16) & 1u);   // round-to-nearest-even
  return (unsigned short)(u >> 16);
}

__device__ __forceinline__ void async_copy16(void* lds, const void* g) {
  __builtin_amdgcn_global_load_lds(
      (const __attribute__((address_space(1))) unsigned int*)g,
      (__attribute__((address_space(3))) unsigned int*)lds,
      16, 0, 0);
}

// ---- zero the s-partials (ws is poisoned 0xAA every call) ----
__global__ void zero_s(float* __restrict__ s) {
  s[blockIdx.x * 256 + threadIdx.x] = 0.0f;
}

// ---- z: fp32 -> out copy + bf16 convert into ws ----
__global__ void convert_copy_z(const float4* __restrict__ z,
                               float4* __restrict__ zout,
                               ushort4* __restrict__ zb) {
  int i = blockIdx.x * 256 + threadIdx.x;
  float4 v = z[i];
  zout[i] = v;
  ushort4 b;
  b.x = f2bf(v.x); b.y = f2bf(v.y); b.z = f2bf(v.z); b.w = f2bf(v.w);
  zb[i] = b;
}

// ---- D [K][N] fp32 -> Dt [N][K] bf16 (so GEMM B reads row-major over K) ----
__global__ void transpose_convert_D(const float* __restrict__ D,
                                    unsigned short* __restrict__ Dt) {
  __shared__ float tile[32][33];
  const int tx = threadIdx.x, ty = threadIdx.y;
  const int nb = blockIdx.x * 32, kb = blockIdx.y * 32;
#pragma unroll
  for (int r = 0; r < 4; ++r)
    tile[ty + r * 8][tx] = D[(size_t)(kb + ty + r * 8) * NZ + nb + tx];
  __syncthreads();
#pragma unroll
  for (int r = 0; r < 4; ++r)
    Dt[(size_t)(nb + ty + r * 8) * NZ + kb + tx] = f2bf(tile[tx][ty + r * 8]);
}

// ---- main: 128x128 tile bf16 MFMA, square+reduce cols -> atomicAdd s ----
__global__ __launch_bounds__(256, 2) void gemm_s(
    const short* __restrict__ zb, const short* __restrict__ dtb,
    float* __restrict__ s_un) {
  __shared__ __align__(16) short A_lds[128 * 32];
  __shared__ __align__(16) short B_lds[128 * 32];

  const int t = threadIdx.x;
  const int w = t >> 6;
  const int lane = t & 63;
  const int quad = lane >> 4;
  const int r16 = lane & 15;
  const int wm = (w >> 1) * 64;
  const int wn = (w & 1) * 64;
  const int m0 = blockIdx.y * 128;
  const int n0 = blockIdx.x * 128;

  // staging: thread t -> 16B chunk; flat LDS layout == row-major [128][32] bf16
  const int sr = t >> 2;            // row 0..63 within half-tile
  const int sk = (t & 3) * 8;       // k offset 0/8/16/24
  const short* ga0 = zb  + (size_t)(m0 + sr) * NZ + sk;
  const short* ga1 = ga0 + (size_t)64 * NZ;
  const short* gb0 = dtb + (size_t)(n0 + sr) * NZ + sk;
  const short* gb1 = gb0 + (size_t)64 * NZ;
  short* la0 = &A_lds[w * 512];            // wave-uniform LDS bases; HW adds lane*16B
  short* la1 = &A_lds[2048 + w * 512];
  short* lb0 = &B_lds[w * 512];
  short* lb1 = &B_lds[2048 + w * 512];

  floatx4 acc[4][4];
#pragma unroll
  for (int i = 0; i < 4; ++i)
#pragma unroll
    for (int j = 0; j < 4; ++j)
      acc[i][j] = {0.0f, 0.0f, 0.0f, 0.0f};

  for (int kt = 0; kt < NZ / 32; ++kt) {
    async_copy16(la0, ga0);
    async_copy16(la1, ga1);
    async_copy16(lb0, gb0);
    async_copy16(lb1, gb1);
    ga0 += 32; ga1 += 32; gb0 += 32; gb1 += 32;
    __syncthreads();   // waits vmcnt(0): LDS tiles landed

    short8 af[4], bf[4];
#pragma unroll
    for (int i = 0; i < 4; ++i) {
      af[i] = *reinterpret_cast<const short8*>(&A_lds[(wm + i * 16 + r16) * 32 + quad * 8]);
      bf[i] = *reinterpret_cast<const short8*>(&B_lds[(wn + i * 16 + r16) * 32 + quad * 8]);
    }
#pragma unroll
    for (int i = 0; i < 4; ++i)
#pragma unroll
      for (int j = 0; j < 4; ++j)
        acc[i][j] = __builtin_amdgcn_mfma_f32_16x16x32_bf16(af[i], bf[j], acc[i][j], 0, 0, 0);
    __syncthreads();   // all waves done reading before next stage overwrites
  }

  // epilogue: sum of squares over this block's 128 cols (all in one cluster)
  const int cluster = n0 >> 9;   // n0 / 512
#pragma unroll
  for (int i = 0; i < 4; ++i) {
    floatx4 v = acc[i][0] * acc[i][0];
#pragma unroll
    for (int j = 1; j < 4; ++j)
      v += acc[i][j] * acc[i][j];
    // reduce across the 16 lanes sharing a quad (same 4 output rows)
#pragma unroll
    for (int m = 1; m < 16; m <<= 1) {
#pragma unroll
      for (int c = 0; c < 4; ++c)
        v[c] += __shfl_xor(v[c], m);
    }
    if (r16 == 0) {
      const int rb = m0 + wm + i * 16 + quad * 4;
      atomicAdd(&s_un[(rb + 0) * NCLUST + cluster], v[0]);
      atomicAdd(&s_un[(rb + 1) * NCLUST + cluster], v[1]);
      atomicAdd(&s_un[(rb + 2) * NCLUST + cluster], v[2]);
      atomicAdd(&s_un[(rb + 3) * NCLUST + cluster], v[3]);
    }
  }
}

// ---- (S + eta*d)/((eta+1)*d), row-normalize ----
__global__ void finalize_s(const float* __restrict__ s_un, float* __restrict__ out) {
  int r = blockIdx.x * 256 + threadIdx.x;
  float v[NCLUST];
  float tot = 0.0f;
#pragma unroll
  for (int i = 0; i < NCLUST; ++i) {
    v[i] = (s_un[r * NCLUST + i] + 2560.0f) * (1.0f / 3072.0f);
    tot += v[i];
  }
  float inv = 1.0f / tot;
#pragma unroll
  for (int i = 0; i < NCLUST; ++i)
    out[r * NCLUST + i] = v[i] * inv;
}

extern "C" void kernel_launch(void* const* d_in, const int* in_sizes, int n_in,
                              void* d_out, int out_size, void* d_ws, size_t ws_size,
                              hipStream_t stream) {
  const float* z = (const float*)d_in[0];
  const float* D = (const float*)d_in[1];
  float* out_s = (float*)d_out;
  float* out_z = out_s + (size_t)NROWS * NCLUST;

  // ws layout: z_bf16 (256 MiB) | Dt_bf16 (128 MiB) | s_unnorm (1 MiB)
  char* ws = (char*)d_ws;
  short* zb = (short*)ws;
  unsigned short* dtb = (unsigned short*)(ws + (size_t)NROWS * NZ * 2);
  float* s_un = (float*)(ws + (size_t)NROWS * NZ * 2 + (size_t)NZ * NZ * 2);

  zero_s<<<(NROWS * NCLUST) / 256, 256, 0, stream>>>(s_un);

  convert_copy_z<<<(int)(((size_t)NROWS * NZ / 4) / 256), 256, 0, stream>>>(
      (const float4*)z, (float4*)out_z, (ushort4*)zb);

  dim3 tg(NZ / 32, NZ / 32);
  transpose_convert_D<<<tg, dim3(32, 8), 0, stream>>>(D, dtb);

  dim3 gg(NZ / 128, NROWS / 128);
  gemm_s<<<gg, 256, 0, stream>>>(zb, (const short*)dtb, s_un);

  finalize_s<<<NROWS / 256, 256, 0, stream>>>(s_un, out_s);
}